// Round 18
// baseline (37.399 us; speedup 1.0000x reference)
//
#include <hip/hip_runtime.h>
#include <stdint.h>

#define B_  16
#define H_  512
#define W_  512
#define HW_ (H_*W_)
#define N_  (B_*HW_)

#define G0 0.054488685f
#define G1 0.244201342f
#define G2 0.402619947f

#define XT 10              // x tiles, 54 valid cols each (lane 5..58)
#define YT 16              // y tiles, 32 rows each
#define NWAVE (XT*YT*B_)   // 2560
#define NBLKC (NWAVE/4)    // 640 blocks x 4 independent waves

__device__ __forceinline__ int reflect512(int i) {
    i = i < 0 ? -i : i;
    return i > 511 ? 1022 - i : i;
}
__device__ __forceinline__ float shfl_f(float v, int abyte) {
    return __int_as_float(__builtin_amdgcn_ds_bpermute(abyte, __float_as_int(v)));
}
__device__ __forceinline__ int shfl_i(int v, int abyte) {
    return __builtin_amdgcn_ds_bpermute(abyte, v);
}

__global__ __launch_bounds__(256)
void k_canny(const float* __restrict__ pred, const float* __restrict__ sketch,
             const float* __restrict__ matte, float* __restrict__ partials)
{
    const int lane = threadIdx.x & 63;
    const int wid  = threadIdx.x >> 6;
    const int tile = blockIdx.x * 4 + wid;
    const int tx = tile % XT;
    const int t2 = tile / XT;
    const int ty = t2 % YT;
    const int b  = t2 / YT;

    const int x  = tx*54 - 5 + lane;       // [-5, 544]
    const int xr = reflect512(x);
    const int y0 = ty*32;

    const float* p0 = pred + (size_t)b*3*HW_ + xr;
    const float* p1 = p0 + HW_;
    const float* p2 = p0 + 2*HW_;
    const float* mp = matte  + (size_t)b*HW_ + xr;
    const float* sp = sketch + (size_t)b*HW_ + xr;

    // bpermute byte addresses (pull from lane +/- k)
    const int am1 = ((lane-1)&63)<<2, ap1 = ((lane+1)&63)<<2;
    const int am2 = ((lane-2)&63)<<2, ap2 = ((lane+2)&63)<<2;

    const bool xin  = (x >= 0) & (x < 512);
    const bool xgt0 = (x > 0), xlt511 = (x < 511);
    const bool lv   = (lane >= 5) & (lane <= 58) & (x < 512);

    // register FIFOs (renamed away by full unroll)
    float g_prev = 0.f;                       // gray row (prev step)
    float t0=0,t1=0,t2f=0,t3=0,t4=0;          // h-blur rows
    float bf0=0,bf1=0,bf2=0;                  // blur rows
    float mf0=0,mf1=0,mf2=0;                  // mag^2 rows (center)
    float mfm0=0,mfm1=0,mfm2=0;               // mag^2 rows shifted left  (x-1)
    float mfp0=0,mfp1=0,mfp2=0;               // mag^2 rows shifted right (x+1)
    int   ox0=0,oy0=0,ox1=0,oy1=0;            // NMS offsets (2-deep)
    int   epk=0;                              // packed class rows e0|e1<<8|e2<<16
    float skA=0,mtA=0,skB=0,mtB=0;            // loss operands (2-deep)
    float mt0=0,mt1=0,mt2=0,mt3=0,mt4=0,mt5=0,mt6=0,mt7=0;  // matte FIFO (depth 8)
    float lacc = 0.f;

    #pragma unroll
    for (int s = 0; s < 47; ++s) {
        // 1) gray load, row yL = y0-5+s (reflected); rows y0-5 .. y0+36
        float vg = 0.f, mv = 0.f;
        if (s <= 41) {
            int o = reflect512(y0 - 5 + s) * W_;
            mv = mp[o];
            vg = (p0[o] + p1[o] + p2[o]) * mv * (1.f/3.f);
        }
        // loss prefetch for row yH(s+2) = y0-13+s; matte comes from the FIFO
        // (stage-1 load 8 steps ago was row y0-5+(s-8) = y0-13+s)
        float nsk = 0.f, nmt = 0.f;
        if (s >= 13 && s <= 44) {
            int o = (y0 - 13 + s)*W_;
            nsk = sp[o];
            nmt = mt0;
        }
        // 2) horizontal gaussian for row y0-6+s (bpermute lane shifts)
        float gm1 = shfl_f(g_prev, am1), gp1v = shfl_f(g_prev, ap1);
        float gm2 = shfl_f(g_prev, am2), gp2v = shfl_f(g_prev, ap2);
        float th = G0*(gm2+gp2v) + G1*(gm1+gp1v) + G2*g_prev;
        // 3) vertical gaussian for row y0-9+s (t-FIFO; reflect handled at load)
        float bl = G0*(t0+t4) + G1*(t1+t3) + G2*t2f;
        // 4) sobel -> mag^2 + NMS offset for row yM = y0-11+s, plus +-1 shuffles
        int yM = y0 - 11 + s;
        float b0e = (yM > 0)   ? bf0 : bf1;      // y replicate
        float b2e = (yM < 511) ? bf2 : bf1;
        float cs  = b0e + 2.f*bf1 + b2e;         // column sum
        float rdv = b2e - b0e;                   // row diff
        float csm = shfl_f(cs, am1),  csp = shfl_f(cs, ap1);
        float rdm = shfl_f(rdv, am1), rdp = shfl_f(rdv, ap1);
        csm = xgt0 ? csm : cs;   csp = xlt511 ? csp : cs;    // x replicate
        rdm = xgt0 ? rdm : rdv;  rdp = xlt511 ? rdp : rdv;
        float gx = csp - csm;
        float gy = rdm + 2.f*rdv + rdp;
        float m2n = fmaf(gx*gx + gy*gy, 0.015625f, 1e-6f);
        bool iny = (yM >= 0) & (yM < 512);
        m2n = (iny & xin) ? m2n : 0.f;           // zero outside image (NMS pad)
        float mneg = shfl_f(m2n, am1);           // row's x-1 values (production-time)
        float mpos = shfl_f(m2n, ap1);           // row's x+1 values
        float agx = fabsf(gx), agy = fabsf(gy);
        int oxn, oyn;
        if      (agy <= 0.41421356f*agx) { oxn = (gx >= 0.f) ? 1 : -1; oyn = 0; }
        else if (agy >= 2.41421356f*agx) { oxn = 0; oyn = (gy > 0.f) ? -1 : 1; }
        else { oxn = (gx > 0.f) ? 1 : -1; oyn = (gy > 0.f) ? -1 : 1; }
        // 5) NMS + double threshold for row yE = y0-13+s (all operands in regs)
        float r0v = (ox0 < 0) ? mfm0 : ((ox0 > 0) ? mfp0 : mf0);
        float r1v = (ox0 < 0) ? mfm1 : ((ox0 > 0) ? mfp1 : mf1);
        float r2v = (ox0 < 0) ? mfm2 : ((ox0 > 0) ? mfp2 : mf2);
        float n1  = (oy0 < 0) ? r0v : ((oy0 > 0) ? r2v : r1v);
        float r0w = (ox0 > 0) ? mfm0 : ((ox0 < 0) ? mfp0 : mf0);
        float r1w = (ox0 > 0) ? mfm1 : ((ox0 < 0) ? mfp1 : mf1);
        float r2w = (ox0 > 0) ? mfm2 : ((ox0 < 0) ? mfp2 : mf2);
        float n2  = (oy0 > 0) ? r0w : ((oy0 < 0) ? r2w : r1w);
        float mc = mf1;
        int cls = 0;
        if (mc > n1 && mc > n2) cls = (mc > 0.01f) + (mc > 0.04f);
        // 6) hysteresis + MSE for output row yH = y0-15+s (packed-class, bpermute)
        if (s >= 15) {
            int epm = shfl_i(epk, am1), epp = shfl_i(epk, ap1);
            int strong = ((epm | epp) & 0x00020202) | (epk & 0x00020002);
            int e1v = (epk >> 8) & 0xff;
            int fin = ((e1v == 1) && strong) ? 2 : e1v;
            float vf = 0.5f * (float)fin;
            float tt = fminf(fmaxf(skA*mtA, 0.f), 1.f);
            float d  = vf - tt;
            lacc += lv ? d*d : 0.f;
        }
        // FIFO shifts (renamed away by unroll)
        g_prev = vg;
        t0=t1; t1=t2f; t2f=t3; t3=t4; t4=th;
        bf0=bf1; bf1=bf2; bf2=bl;
        mf0=mf1;   mf1=mf2;   mf2=m2n;
        mfm0=mfm1; mfm1=mfm2; mfm2=mneg;
        mfp0=mfp1; mfp1=mfp2; mfp2=mpos;
        ox0=ox1; oy0=oy1; ox1=oxn; oy1=oyn;
        epk = (epk >> 8) | (cls << 16);
        skA=skB; mtA=mtB; skB=nsk; mtB=nmt;
        mt0=mt1; mt1=mt2; mt2=mt3; mt3=mt4; mt4=mt5; mt5=mt6; mt6=mt7; mt7=mv;
    }

    #pragma unroll
    for (int off = 32; off > 0; off >>= 1)
        lacc += __shfl_down(lacc, off, 64);
    if (lane == 0) partials[tile] = lacc;
}

__global__ __launch_bounds__(256)
void k_final(const float* __restrict__ partials, float* __restrict__ out) {
    int tid = threadIdx.x;
    float acc = 0.f;
    #pragma unroll
    for (int j = 0; j < NWAVE/256; ++j)           // 10 scalars per thread
        acc += partials[j*256 + tid];
    #pragma unroll
    for (int off = 32; off > 0; off >>= 1)
        acc += __shfl_down(acc, off, 64);
    __shared__ float ws[4];
    if ((tid & 63) == 0) ws[tid >> 6] = acc;
    __syncthreads();
    if (tid == 0) out[0] = (ws[0] + ws[1] + ws[2] + ws[3]) * (1.0f / (float)N_);
}

extern "C" void kernel_launch(void* const* d_in, const int* in_sizes, int n_in,
                              void* d_out, int out_size, void* d_ws, size_t ws_size,
                              hipStream_t stream) {
    const float* pred   = (const float*)d_in[0];
    const float* sketch = (const float*)d_in[1];
    const float* matte  = (const float*)d_in[2];
    float* out = (float*)d_out;
    float* partials = (float*)d_ws;   // NWAVE floats

    k_canny<<<NBLKC, 256, 0, stream>>>(pred, sketch, matte, partials);
    k_final<<<1, 256, 0, stream>>>(partials, out);
}

// Round 19
// 31.697 us; speedup vs baseline: 1.1799x; 1.1799x over previous
//
#include <hip/hip_runtime.h>
#include <stdint.h>

#define B_  16
#define H_  512
#define W_  512
#define HW_ (H_*W_)
#define N_  (B_*HW_)

#define G0 0.054488685f
#define G1 0.244201342f
#define G2 0.402619947f

#define XT 10              // x tiles, 54 valid cols each (lane 5..58)
#define YT 32              // y tiles, 16 rows each
#define NWAVE (XT*YT*B_)   // 5120
#define NBLKC (NWAVE/4)    // 1280 blocks x 4 independent waves

__device__ __forceinline__ int reflect512(int i) {
    i = i < 0 ? -i : i;
    return i > 511 ? 1022 - i : i;
}
__device__ __forceinline__ float shfl_f(float v, int abyte) {
    return __int_as_float(__builtin_amdgcn_ds_bpermute(abyte, __float_as_int(v)));
}
__device__ __forceinline__ int shfl_i(int v, int abyte) {
    return __builtin_amdgcn_ds_bpermute(abyte, v);
}

__global__ __launch_bounds__(256)
void k_canny(const float* __restrict__ pred, const float* __restrict__ sketch,
             const float* __restrict__ matte, float* __restrict__ partials)
{
    const int lane = threadIdx.x & 63;
    const int wid  = threadIdx.x >> 6;
    const int tile = blockIdx.x * 4 + wid;
    const int tx = tile % XT;
    const int t2 = tile / XT;
    const int ty = t2 % YT;
    const int b  = t2 / YT;

    const int x  = tx*54 - 5 + lane;       // [-5, 544]
    const int xr = reflect512(x);
    const int y0 = ty*16;

    const float* p0 = pred + (size_t)b*3*HW_ + xr;
    const float* p1 = p0 + HW_;
    const float* p2 = p0 + 2*HW_;
    const float* mp = matte  + (size_t)b*HW_ + xr;
    const float* sp = sketch + (size_t)b*HW_ + xr;

    // bpermute byte addresses (pull from lane +/- k)
    const int am1 = ((lane-1)&63)<<2, ap1 = ((lane+1)&63)<<2;
    const int am2 = ((lane-2)&63)<<2, ap2 = ((lane+2)&63)<<2;

    const bool xin  = (x >= 0) & (x < 512);
    const bool xgt0 = (x > 0), xlt511 = (x < 511);
    const bool lv   = (lane >= 5) & (lane <= 58) & (x < 512);

    // register FIFOs (renamed away by full unroll)
    float g_prev = 0.f;                       // gray row (prev step)
    float t0=0,t1=0,t2f=0,t3=0,t4=0;          // h-blur rows
    float bf0=0,bf1=0,bf2=0;                  // blur rows
    float mf0=0,mf1=0,mf2=0;                  // mag^2 rows (center)
    float mfm0=0,mfm1=0,mfm2=0;               // mag^2 rows shifted left  (x-1)
    float mfp0=0,mfp1=0,mfp2=0;               // mag^2 rows shifted right (x+1)
    int   ox0=0,oy0=0,ox1=0,oy1=0;            // NMS offsets (2-deep)
    int   epk=0;                              // packed class rows e0|e1<<8|e2<<16
    float skA=0,mtA=0,skB=0,mtB=0;            // loss operands (2-deep)
    float mq0=0,mq1=0,mq2=0,mq3=0,mq4=0,mq5=0,mq6=0,mq7=0;  // matte FIFO (depth 8)
    float lacc = 0.f;

    #pragma unroll
    for (int s = 0; s < 31; ++s) {
        // 1) gray load, row yL = y0-5+s (reflected); rows y0-5 .. y0+20
        float vg = 0.f, mv = 0.f;
        if (s <= 25) {
            int o = reflect512(y0 - 5 + s) * W_;
            mv = mp[o];
            vg = (p0[o] + p1[o] + p2[o]) * mv * (1.f/3.f);
        }
        // loss prefetch for row yH(s+2) = y0-13+s; matte from the FIFO
        // (stage-1 load 8 steps ago was row y0-5+(s-8) = y0-13+s, in [y0,y0+15])
        float nsk = 0.f, nmt = 0.f;
        if (s >= 13 && s <= 28) {
            int o = (y0 - 13 + s)*W_;
            nsk = sp[o];
            nmt = mq0;
        }
        // 2) horizontal gaussian for row y0-6+s (bpermute lane shifts)
        float gm1 = shfl_f(g_prev, am1), gp1v = shfl_f(g_prev, ap1);
        float gm2 = shfl_f(g_prev, am2), gp2v = shfl_f(g_prev, ap2);
        float th = G0*(gm2+gp2v) + G1*(gm1+gp1v) + G2*g_prev;
        // 3) vertical gaussian for row y0-9+s (t-FIFO; reflect handled at load)
        float bl = G0*(t0+t4) + G1*(t1+t3) + G2*t2f;
        // 4) sobel -> mag^2 + NMS offset for row yM = y0-11+s, plus +-1 shuffles
        int yM = y0 - 11 + s;
        float b0e = (yM > 0)   ? bf0 : bf1;      // y replicate
        float b2e = (yM < 511) ? bf2 : bf1;
        float cs  = b0e + 2.f*bf1 + b2e;         // column sum
        float rdv = b2e - b0e;                   // row diff
        float csm = shfl_f(cs, am1),  csp = shfl_f(cs, ap1);
        float rdm = shfl_f(rdv, am1), rdp = shfl_f(rdv, ap1);
        csm = xgt0 ? csm : cs;   csp = xlt511 ? csp : cs;    // x replicate
        rdm = xgt0 ? rdm : rdv;  rdp = xlt511 ? rdp : rdv;
        float gx = csp - csm;
        float gy = rdm + 2.f*rdv + rdp;
        float m2n = fmaf(gx*gx + gy*gy, 0.015625f, 1e-6f);
        bool iny = (yM >= 0) & (yM < 512);
        m2n = (iny & xin) ? m2n : 0.f;           // zero outside image (NMS pad)
        float mneg = shfl_f(m2n, am1);           // row's x-1 values (production-time)
        float mpos = shfl_f(m2n, ap1);           // row's x+1 values
        float agx = fabsf(gx), agy = fabsf(gy);
        int oxn, oyn;
        if      (agy <= 0.41421356f*agx) { oxn = (gx >= 0.f) ? 1 : -1; oyn = 0; }
        else if (agy >= 2.41421356f*agx) { oxn = 0; oyn = (gy > 0.f) ? -1 : 1; }
        else { oxn = (gx > 0.f) ? 1 : -1; oyn = (gy > 0.f) ? -1 : 1; }
        // 5) NMS + double threshold for row yE = y0-13+s (all operands in regs)
        float r0v = (ox0 < 0) ? mfm0 : ((ox0 > 0) ? mfp0 : mf0);
        float r1v = (ox0 < 0) ? mfm1 : ((ox0 > 0) ? mfp1 : mf1);
        float r2v = (ox0 < 0) ? mfm2 : ((ox0 > 0) ? mfp2 : mf2);
        float n1  = (oy0 < 0) ? r0v : ((oy0 > 0) ? r2v : r1v);
        float r0w = (ox0 > 0) ? mfm0 : ((ox0 < 0) ? mfp0 : mf0);
        float r1w = (ox0 > 0) ? mfm1 : ((ox0 < 0) ? mfp1 : mf1);
        float r2w = (ox0 > 0) ? mfm2 : ((ox0 < 0) ? mfp2 : mf2);
        float n2  = (oy0 > 0) ? r0w : ((oy0 < 0) ? r2w : r1w);
        float mc = mf1;
        int cls = 0;
        if (mc > n1 && mc > n2) cls = (mc > 0.01f) + (mc > 0.04f);
        // 6) hysteresis + MSE for output row yH = y0-15+s (packed-class, bpermute)
        if (s >= 15) {
            int epm = shfl_i(epk, am1), epp = shfl_i(epk, ap1);
            int strong = ((epm | epp) & 0x00020202) | (epk & 0x00020002);
            int e1v = (epk >> 8) & 0xff;
            int fin = ((e1v == 1) && strong) ? 2 : e1v;
            float vf = 0.5f * (float)fin;
            float tt = fminf(fmaxf(skA*mtA, 0.f), 1.f);
            float d  = vf - tt;
            lacc += lv ? d*d : 0.f;
        }
        // FIFO shifts (renamed away by unroll)
        g_prev = vg;
        t0=t1; t1=t2f; t2f=t3; t3=t4; t4=th;
        bf0=bf1; bf1=bf2; bf2=bl;
        mf0=mf1;   mf1=mf2;   mf2=m2n;
        mfm0=mfm1; mfm1=mfm2; mfm2=mneg;
        mfp0=mfp1; mfp1=mfp2; mfp2=mpos;
        ox0=ox1; oy0=oy1; ox1=oxn; oy1=oyn;
        epk = (epk >> 8) | (cls << 16);
        skA=skB; mtA=mtB; skB=nsk; mtB=nmt;
        mq0=mq1; mq1=mq2; mq2=mq3; mq3=mq4; mq4=mq5; mq5=mq6; mq6=mq7; mq7=mv;
    }

    #pragma unroll
    for (int off = 32; off > 0; off >>= 1)
        lacc += __shfl_down(lacc, off, 64);
    if (lane == 0) partials[tile] = lacc;
}

__global__ __launch_bounds__(256)
void k_final(const float* __restrict__ partials, float* __restrict__ out) {
    int tid = threadIdx.x;
    float acc = 0.f;
    const float4* p4 = (const float4*)partials;
    #pragma unroll
    for (int j = 0; j < NWAVE/1024; ++j) {          // 5 float4 per thread
        float4 v = p4[j*256 + tid];
        acc += (v.x + v.y) + (v.z + v.w);
    }
    #pragma unroll
    for (int off = 32; off > 0; off >>= 1)
        acc += __shfl_down(acc, off, 64);
    __shared__ float ws[4];
    if ((tid & 63) == 0) ws[tid >> 6] = acc;
    __syncthreads();
    if (tid == 0) out[0] = (ws[0] + ws[1] + ws[2] + ws[3]) * (1.0f / (float)N_);
}

extern "C" void kernel_launch(void* const* d_in, const int* in_sizes, int n_in,
                              void* d_out, int out_size, void* d_ws, size_t ws_size,
                              hipStream_t stream) {
    const float* pred   = (const float*)d_in[0];
    const float* sketch = (const float*)d_in[1];
    const float* matte  = (const float*)d_in[2];
    float* out = (float*)d_out;
    float* partials = (float*)d_ws;   // NWAVE floats

    k_canny<<<NBLKC, 256, 0, stream>>>(pred, sketch, matte, partials);
    k_final<<<1, 256, 0, stream>>>(partials, out);
}